// Round 11
// baseline (684.215 us; speedup 1.0000x reference)
//
#include <hip/hip_runtime.h>

#define NEG_SLOPE 0.2f
#define EPS_ 1e-9f

typedef __attribute__((ext_vector_type(8))) short short8v;
typedef __attribute__((ext_vector_type(4))) float f32x4;

__device__ __forceinline__ float bf2f(unsigned short u) {
    return __uint_as_float(((unsigned)u) << 16);
}
__device__ __forceinline__ unsigned short f2bf(float f) {
    unsigned u = __float_as_uint(f);
    u = u + 0x7FFFu + ((u >> 16) & 1u);   // round-to-nearest-even
    return (unsigned short)(u >> 16);
}

// ==================== CSR build (both graphs via blockIdx.y) ====================
__global__ void hist_kernel(const int* __restrict__ srcA, const int* __restrict__ srcB,
        int* __restrict__ cnt, int E, int n) {
    int g = blockIdx.y;
    const int* src = g ? srcB : srcA;
    int* c = cnt + (size_t)g * n;
    int i = blockIdx.x * blockDim.x + threadIdx.x;
    if (i < E) atomicAdd(&c[src[i]], 1);
}

__global__ __launch_bounds__(256) void scan1_kernel(const int* __restrict__ cnt,
        int* __restrict__ locpre, int* __restrict__ blocksum, int n, int nb) {
    int g = blockIdx.y;
    const int* cg = cnt + (size_t)g * n;
    int* lg = locpre + (size_t)g * n;
    int* bs = blocksum + (size_t)g * nb;
    int t = threadIdx.x;
    int lane = t & 63, wid = t >> 6;
    int base = blockIdx.x * 1024 + t * 4;
    int4 v = {0, 0, 0, 0};
    if (base + 3 < n) {
        v = *(const int4*)(cg + base);
    } else {
        if (base + 0 < n) v.x = cg[base + 0];
        if (base + 1 < n) v.y = cg[base + 1];
        if (base + 2 < n) v.z = cg[base + 2];
        if (base + 3 < n) v.w = cg[base + 3];
    }
    int s = v.x + v.y + v.z + v.w;
    int incl = s;
    for (int off = 1; off < 64; off <<= 1) {
        int u = __shfl_up(incl, off);
        if (lane >= off) incl += u;
    }
    __shared__ int ws[4];
    if (lane == 63) ws[wid] = incl;
    __syncthreads();
    int woff = 0;
    for (int i = 0; i < wid; ++i) woff += ws[i];
    int excl = incl - s + woff;
    int4 o;
    o.x = excl; o.y = excl + v.x; o.z = o.y + v.y; o.w = o.z + v.z;
    if (base + 3 < n) {
        *(int4*)(lg + base) = o;
    } else {
        if (base + 0 < n) lg[base + 0] = o.x;
        if (base + 1 < n) lg[base + 1] = o.y;
        if (base + 2 < n) lg[base + 2] = o.z;
        if (base + 3 < n) lg[base + 3] = o.w;
    }
    if (t == 255) bs[blockIdx.x] = excl + s;
}

__global__ __launch_bounds__(64) void scan2_kernel(int* __restrict__ blocksum, int nb,
        int* __restrict__ row_ptr, int n) {
    int g = blockIdx.y;
    int* bs = blocksum + (size_t)g * nb;
    int lane = threadIdx.x;
    int carry = 0;
    for (int base = 0; base < nb; base += 64) {
        int v = (base + lane < nb) ? bs[base + lane] : 0;
        int incl = v;
        for (int off = 1; off < 64; off <<= 1) {
            int u = __shfl_up(incl, off);
            if (lane >= off) incl += u;
        }
        int tot = __shfl(incl, 63);
        if (base + lane < nb) bs[base + lane] = incl - v + carry;
        carry += tot;
    }
    if (lane == 0) row_ptr[(size_t)g * (n + 1) + n] = carry;   // == E
}

__global__ __launch_bounds__(256) void scan3_kernel(const int* __restrict__ locpre,
        const int* __restrict__ blocksum, int* __restrict__ row_ptr,
        int* __restrict__ cursor, int n, int nb) {
    int g = blockIdx.y;
    const int* lg = locpre + (size_t)g * n;
    const int* bs = blocksum + (size_t)g * nb;
    int* rp = row_ptr + (size_t)g * (n + 1);
    int* cu = cursor + (size_t)g * n;
    int base = blockIdx.x * 1024 + threadIdx.x * 4;
    int off = bs[blockIdx.x];
    if (base + 3 < n) {
        int4 v = *(const int4*)(lg + base);
        v.x += off; v.y += off; v.z += off; v.w += off;
        *(int4*)(rp + base) = v;
        *(int4*)(cu + base) = v;
    } else {
        for (int i = 0; i < 4; ++i) {
            if (base + i < n) {
                int v = lg[base + i] + off;
                rp[base + i] = v;
                cu[base + i] = v;
            }
        }
    }
}

__global__ void scatter_kernel(const int* __restrict__ srcA, const int* __restrict__ dstA,
        const int* __restrict__ srcB, const int* __restrict__ dstB,
        int* __restrict__ cursor, int* __restrict__ colv, int E, int n, int ecap) {
    int g = blockIdx.y;
    const int* src = g ? srcB : srcA;
    const int* dst = g ? dstB : dstA;
    int* cu = cursor + (size_t)g * n;
    int* cv = colv + (size_t)g * ecap;
    int i = blockIdx.x * blockDim.x + threadIdx.x;
    if (i < E) {
        int p = atomicAdd(&cu[src[i]], 1);
        cv[p] = dst[i];
    }
}

// ==================== W transpose + bf16 convert ====================
__global__ void wt_kernel(const float* __restrict__ W, short* __restrict__ Wt) {
    int nn = blockIdx.x, k = threadIdx.x;
    Wt[nn * 256 + k] = (short)f2bf(W[k * 256 + nn]);   // Wt[n][k] = W[k][n]
}

// ==================== GEMM: h' = h @ W, B-half resident in LDS ====================
__global__ __launch_bounds__(512) void gemm_kernel(const float* __restrict__ hinA,
        const float* __restrict__ hinB, const short* __restrict__ Wt,
        unsigned short* __restrict__ hpS_all, int M) {
    __shared__ short Bt[32768];   // 64 KB exact
    int tid = threadIdx.x;
    int lane = tid & 63, w = tid >> 6;
    int ch = blockIdx.y;
    int g = blockIdx.z;
    const float* hin = g ? hinB : hinA;
    unsigned short* hpS = hpS_all + (size_t)g * M * 256;

    // ---- load B half (128 cols x 256 k) into LDS ----
    {
        int n = tid >> 2;
        int kb = (tid & 3) * 64;
        const short* srcw = Wt + (size_t)(ch * 128 + n) * 256;
#pragma unroll
        for (int i = 0; i < 8; ++i) {
            int k = kb + i * 8;
            short8v v = *(const short8v*)(srcw + k);
            *(short8v*)&Bt[((k >> 3) * 128 + n) * 8] = v;
        }
    }
    __syncthreads();

    int row0 = (blockIdx.x * 8 + w) * 16;
    if (row0 >= M) return;                 // M % 16 == 0, so full tiles only

    // ---- A fragments: row = lane&15, k = c*32 + (lane>>4)*8 ----
    const float* Ap = hin + (size_t)(row0 + (lane & 15)) * 256 + (lane >> 4) * 8;
    short8v af[8];
#pragma unroll
    for (int half = 0; half < 2; ++half) {
        float4 u0[4], u1[4];
#pragma unroll
        for (int c = 0; c < 4; ++c) {
            u0[c] = *(const float4*)(Ap + (half * 4 + c) * 32);
            u1[c] = *(const float4*)(Ap + (half * 4 + c) * 32 + 4);
        }
#pragma unroll
        for (int c = 0; c < 4; ++c) {
            short8v a;
            a[0] = (short)f2bf(u0[c].x); a[1] = (short)f2bf(u0[c].y);
            a[2] = (short)f2bf(u0[c].z); a[3] = (short)f2bf(u0[c].w);
            a[4] = (short)f2bf(u1[c].x); a[5] = (short)f2bf(u1[c].y);
            a[6] = (short)f2bf(u1[c].z); a[7] = (short)f2bf(u1[c].w);
            af[half * 4 + c] = a;
        }
    }

    f32x4 acc[8];
#pragma unroll
    for (int t = 0; t < 8; ++t) acc[t] = (f32x4){0.f, 0.f, 0.f, 0.f};

#pragma unroll
    for (int c = 0; c < 8; ++c) {
        int kcf = c * 4 + (lane >> 4);
#pragma unroll
        for (int t = 0; t < 8; ++t) {
            short8v b = *(const short8v*)&Bt[(kcf * 128 + t * 16 + (lane & 15)) * 8];
            acc[t] = __builtin_amdgcn_mfma_f32_16x16x32_bf16(af[c], b, acc[t], 0, 0, 0);
        }
    }

    // ---- epilogue: slice-major store hpS[col>>5][row][col&31] ----
    size_t Ns = (size_t)M * 32;
#pragma unroll
    for (int t = 0; t < 8; ++t) {
        int col = ch * 128 + t * 16 + (lane & 15);
        unsigned short* dst = hpS + (size_t)(col >> 5) * Ns + (col & 31);
#pragma unroll
        for (int j = 0; j < 4; ++j) {
            int row = row0 + (lane >> 4) * 4 + j;
            dst[(size_t)row * 32] = f2bf(acc[t][j]);
        }
    }
}

// ==================== alpha: per-node exp-tables from hpS (both graphs) =========
// fsrc2[v] = {e^-asrc, e^-0.2asrc}, fdst2[v] = {e^-adst, e^-0.2adst}:
// w_edge = exp(-lrelu(asrc+adst)) == min(e^-a * e^-d, e^-0.2a * e^-0.2d)
// (exact identity; x>=0 picks exp(-x), x<0 picks exp(-0.2x)).
// This removes ALL transcendentals from the aggregate inner loop (R10: each
// edge's exp was recomputed 8 slices x 8 lanes = 64x -> VALUBusy 72%).
__global__ __launch_bounds__(256) void alpha_kernel(const unsigned short* __restrict__ hpS,
        const float* __restrict__ a, float2* __restrict__ fsrc2,
        float2* __restrict__ fdst2, int n) {
    int gid = (blockIdx.x * 256 + threadIdx.x) >> 3;   // node id across 2N
    int ln8 = threadIdx.x & 7;
    if (gid >= 2 * n) return;
    int g = gid >= n;
    int node = gid - g * n;
    const unsigned short* base = hpS + (size_t)g * n * 256;
    float s0 = 0.f, s1 = 0.f;
#pragma unroll
    for (int s = 0; s < 8; ++s) {
        uint2 q = *(const uint2*)(base + (size_t)s * ((size_t)n * 32)
                                  + (size_t)node * 32 + ln8 * 4);
        float f0 = __uint_as_float(q.x << 16);
        float f1 = __uint_as_float(q.x & 0xFFFF0000u);
        float f2 = __uint_as_float(q.y << 16);
        float f3 = __uint_as_float(q.y & 0xFFFF0000u);
        int ax = s * 32 + ln8 * 4;
        s0 += f0 * a[ax] + f1 * a[ax + 1] + f2 * a[ax + 2] + f3 * a[ax + 3];
        s1 += f0 * a[256 + ax] + f1 * a[257 + ax] + f2 * a[258 + ax] + f3 * a[259 + ax];
    }
    for (int off = 1; off < 8; off <<= 1) {
        s0 += __shfl_xor(s0, off);
        s1 += __shfl_xor(s1, off);
    }
    if (ln8 == 0) {
        fsrc2[gid] = make_float2(__expf(-s0), __expf(-NEG_SLOPE * s0));
        fdst2[gid] = make_float2(__expf(-s1), __expf(-NEG_SLOPE * s1));
    }
}

// ==================== aggregation: 8 nodes x 1 slice per wave ====================
// slice = blockIdx.x&7 (XCD-affine; 3.2MB slice + 400KB fdst2 table < 4MB L2).
// Per-edge weight = 2 mul + 1 min (exp-free, see alpha_kernel). 8-deep batch.
__global__ __launch_bounds__(256) void aggregate_kernel(const int* __restrict__ row_ptr,
        const int* __restrict__ colv, const float2* __restrict__ fsrc2,
        const float2* __restrict__ fdst2, const unsigned short* __restrict__ hpS,
        float* __restrict__ outp, int n, int ecap) {
    int slice = blockIdx.x & 7;
    int ngrp = blockIdx.x >> 3;
    int g = blockIdx.y;
    int wid = threadIdx.x >> 6, lane = threadIdx.x & 63;
    int node = ngrp * 32 + wid * 8 + (lane >> 3);
    int c4 = (lane & 7) * 4;
    bool valid = node < n;
    int nd = valid ? node : 0;
    const int* rp = row_ptr + (size_t)g * (n + 1);
    int beg = rp[nd];
    int end = valid ? rp[nd + 1] : beg;
    int last = end - 1;
    const int* cv = colv + (size_t)g * ecap;
    const float2* fd = fdst2 + (size_t)g * n;
    float2 es = fsrc2[(size_t)g * n + nd];
    const unsigned short* base = hpS + (size_t)g * n * 256 + (size_t)slice * ((size_t)n * 32);

    float acc0 = 0.f, acc1 = 0.f, acc2 = 0.f, acc3 = 0.f, rs = 0.f;
#define JLD(jj, kk) int jj = cv[min(e + kk, last)];
#define DGA(dd, jj) float2 dd = fd[jj];
#define HGA(qq, jj) uint2 qq = *(const uint2*)(base + (size_t)(unsigned)jj * 32 + c4);
#define WCMP(ww, dd, kk) float ww = (kk < m) ? fminf(es.x * dd.x, es.y * dd.y) : 0.f;
#define ACC(qq, ww) { \
    acc0 = fmaf(ww, __uint_as_float(qq.x << 16), acc0); \
    acc1 = fmaf(ww, __uint_as_float(qq.x & 0xFFFF0000u), acc1); \
    acc2 = fmaf(ww, __uint_as_float(qq.y << 16), acc2); \
    acc3 = fmaf(ww, __uint_as_float(qq.y & 0xFFFF0000u), acc3); \
    rs += ww; }

    for (int e = beg; e < end; e += 8) {
        int m = end - e;
        JLD(j0, 0) JLD(j1, 1) JLD(j2, 2) JLD(j3, 3)
        JLD(j4, 4) JLD(j5, 5) JLD(j6, 6) JLD(j7, 7)
        DGA(d0, j0) DGA(d1, j1) DGA(d2, j2) DGA(d3, j3)
        DGA(d4, j4) DGA(d5, j5) DGA(d6, j6) DGA(d7, j7)
        HGA(q0, j0) HGA(q1, j1) HGA(q2, j2) HGA(q3, j3)
        HGA(q4, j4) HGA(q5, j5) HGA(q6, j6) HGA(q7, j7)
        WCMP(w0, d0, 0) WCMP(w1, d1, 1) WCMP(w2, d2, 2) WCMP(w3, d3, 3)
        WCMP(w4, d4, 4) WCMP(w5, d5, 5) WCMP(w6, d6, 6) WCMP(w7, d7, 7)
        ACC(q0, w0) ACC(q1, w1) ACC(q2, w2) ACC(q3, w3)
        ACC(q4, w4) ACC(q5, w5) ACC(q6, w6) ACC(q7, w7)
    }
    if (valid) {
        float inv = 1.f / (rs + EPS_);
        float v0 = acc0 * inv, v1 = acc1 * inv, v2 = acc2 * inv, v3 = acc3 * inv;
        v0 = v0 > 0.f ? v0 : __expf(v0) - 1.f;   // ELU
        v1 = v1 > 0.f ? v1 : __expf(v1) - 1.f;
        v2 = v2 > 0.f ? v2 : __expf(v2) - 1.f;
        v3 = v3 > 0.f ? v3 : __expf(v3) - 1.f;
        float4 ov = {v0, v1, v2, v3};
        *(float4*)(outp + (size_t)g * n * 256 + (size_t)node * 256 + slice * 32 + c4) = ov;
    }
}

extern "C" void kernel_launch(void* const* d_in, const int* in_sizes, int n_in,
                              void* d_out, int out_size, void* d_ws, size_t ws_size,
                              hipStream_t stream) {
    const float* sr_emb = (const float*)d_in[0];
    const float* tg_emb = (const float*)d_in[1];
    const float* W1 = (const float*)d_in[2];
    const float* a1 = (const float*)d_in[3];
    const float* W2 = (const float*)d_in[4];
    const float* a2 = (const float*)d_in[5];
    const int* adj_sr = (const int*)d_in[6];
    const int* adj_tg = (const int*)d_in[7];
    int N = in_sizes[0] / 256;
    int E = in_sizes[6] / 2;

    char* p = (char*)d_ws;
    auto alloc = [&](size_t bytes) -> void* {
        void* r = (void*)p;
        p += (bytes + 255) & ~(size_t)255;
        return r;
    };
    int nb = (N + 1023) / 1024;
    int ecap = E + 8;
    int* cnt      = (int*)alloc((size_t)2 * N * 4);
    int* row_ptr  = (int*)alloc((size_t)2 * (N + 1) * 4);
    int* cursor   = (int*)alloc((size_t)2 * N * 4);
    int* locpre   = (int*)alloc((size_t)2 * N * 4);
    int* blocksum = (int*)alloc((size_t)2 * nb * 4);
    int* colv     = (int*)alloc((size_t)2 * ecap * 4);
    short* Wt1    = (short*)alloc(256 * 256 * 2);
    short* Wt2    = (short*)alloc(256 * 256 * 2);
    unsigned short* hpS = (unsigned short*)alloc((size_t)2 * N * 256 * 2); // [g][8][N][32]
    float2* fsrc2 = (float2*)alloc((size_t)2 * N * 8);
    float2* fdst2 = (float2*)alloc((size_t)2 * N * 8);
    float* outf   = (float*)d_out;   // layer-1 tmp (f32) AND final output

    // ---- CSR build, both graphs ----
    hipMemsetAsync(cnt, 0, (size_t)2 * N * 4, stream);
    wt_kernel<<<256, 256, 0, stream>>>(W1, Wt1);
    wt_kernel<<<256, 256, 0, stream>>>(W2, Wt2);
    int e_grid = (E + 255) / 256;
    hist_kernel<<<dim3(e_grid, 2), 256, 0, stream>>>(adj_sr, adj_tg, cnt, E, N);
    scan1_kernel<<<dim3(nb, 2), 256, 0, stream>>>(cnt, locpre, blocksum, N, nb);
    scan2_kernel<<<dim3(1, 2), 64, 0, stream>>>(blocksum, nb, row_ptr, N);
    scan3_kernel<<<dim3(nb, 2), 256, 0, stream>>>(locpre, blocksum, row_ptr, cursor, N, nb);
    scatter_kernel<<<dim3(e_grid, 2), 256, 0, stream>>>(adj_sr, adj_sr + E,
            adj_tg, adj_tg + E, cursor, colv, E, N, ecap);

    int gemm_rt = (N + 127) / 128;
    int alpha_grid = (2 * N + 31) / 32;
    int agg_gx = 8 * ((N + 31) / 32);

    // ---- layer 1: emb(f32) -> hpS -> alpha -> aggregate -> d_out (f32 tmp) ----
    gemm_kernel<<<dim3(gemm_rt, 2, 2), 512, 0, stream>>>(sr_emb, tg_emb, Wt1, hpS, N);
    alpha_kernel<<<alpha_grid, 256, 0, stream>>>(hpS, a1, fsrc2, fdst2, N);
    aggregate_kernel<<<dim3(agg_gx, 2), 256, 0, stream>>>(row_ptr, colv, fsrc2, fdst2,
            hpS, outf, N, ecap);
    // ---- layer 2: d_out(f32) -> hpS -> alpha -> aggregate -> d_out (final) ----
    gemm_kernel<<<dim3(gemm_rt, 2, 2), 512, 0, stream>>>(outf, outf + (size_t)N * 256,
            Wt2, hpS, N);
    alpha_kernel<<<alpha_grid, 256, 0, stream>>>(hpS, a2, fsrc2, fdst2, N);
    aggregate_kernel<<<dim3(agg_gx, 2), 256, 0, stream>>>(row_ptr, colv, fsrc2, fdst2,
            hpS, outf, N, ecap);
}